// Round 10
// baseline (205.314 us; speedup 1.0000x reference)
//
#include <hip/hip_runtime.h>
#include <stdint.h>

// Problem constants
#define K_DIM   2048      // IN_DIM
#define NN      2047      // N_NODES
#define NPAD    2048      // padded node dim
#define BATCH   16384
#define ODIM    10
#define IOFF    (128 * 2048)   // +128 rows in elements

typedef __attribute__((ext_vector_type(8))) short  bf16x8;
typedef __attribute__((ext_vector_type(4))) float  f32x4;

static __device__ __forceinline__ unsigned short f2bf(float f) {
    union { float f; unsigned int u; } c; c.f = f;
    unsigned int u = c.u;
    return (unsigned short)((u + 0x7fffu + ((u >> 16) & 1u)) >> 16);
}
static __device__ __forceinline__ float bf2f(unsigned short h) {
    union { unsigned int u; float f; } c; c.u = ((unsigned int)h) << 16;
    return c.f;
}

// ---------------- fused fp32 -> bf16 conversion: in_x and padded W1 ----------------
__global__ __launch_bounds__(256) void cvt_all(const float* __restrict__ xs,
                                               const float* __restrict__ ws,
                                               unsigned short* __restrict__ dx,
                                               unsigned short* __restrict__ dw) {
    int b = blockIdx.x;
    union { unsigned short h[8]; uint4 v; } o;
    if (b < 16384) {
        int i = b * 256 + threadIdx.x;
        const float4* s = (const float4*)xs + (size_t)i * 2;
        float4 a = s[0], c = s[1];
        o.h[0] = f2bf(a.x); o.h[1] = f2bf(a.y); o.h[2] = f2bf(a.z); o.h[3] = f2bf(a.w);
        o.h[4] = f2bf(c.x); o.h[5] = f2bf(c.y); o.h[6] = f2bf(c.z); o.h[7] = f2bf(c.w);
        *((uint4*)dx + i) = o.v;
    } else {
        int i = (b - 16384) * 256 + threadIdx.x;
        size_t e = (size_t)i * 8;
        int row = (int)(e >> 11);
        if (row < NN) {
            const float4* s = (const float4*)(ws + e);
            float4 a = s[0], c = s[1];
            o.h[0] = f2bf(a.x); o.h[1] = f2bf(a.y); o.h[2] = f2bf(a.z); o.h[3] = f2bf(a.w);
            o.h[4] = f2bf(c.x); o.h[5] = f2bf(c.y); o.h[6] = f2bf(c.z); o.h[7] = f2bf(c.w);
        } else {
            o.v = make_uint4(0u, 0u, 0u, 0u);
        }
        *((uint4*)dw + i) = o.v;
    }
}

// ---------------- 256x256 bf16 GEMM, BK=32, 4 LDS bufs, register double-buffered frags ----------------
// Tile T: [stage(T+3) | ds_read frags of T+1 -> R_nxt | MFMA on R_cur (no lgkm dep) | VM4 | BAR].
// MFMAs issue right after the barrier; reads overlap the MFMA stream and have a full tile to land.
// VM4 at end of T retires stages <= T-1 => buf T+2 ready before its reads during T+1.
__global__ __launch_bounds__(512, 1) void gemmK(const unsigned short* __restrict__ A,
                                                const unsigned short* __restrict__ B,
                                                const float* __restrict__ bias,
                                                unsigned short* __restrict__ X) {
    __shared__ char lds[131072];   // 4 bufs x (A 16KB + B 16KB)

    const int t0   = threadIdx.x;
    const int w    = t0 >> 6;
    const int lane = t0 & 63;
    const int wm = w >> 2, wn = w & 3;     // wave -> 128 rows x 64 cols
    const int lr = lane & 15, lk = lane >> 4;

    // XCD-aware swizzle: 512 wgs, 64 per XCD
    int bid = blockIdx.x;
    int swz = (bid & 7) * 64 + (bid >> 3);
    const int rowBase = (swz >> 3) * 256;  // 64 row-tiles
    const int colBase = (swz & 7) * 256;   // 8 col-tiles

    // ---- staging source (inverse-swizzled), R9 verbatim ----
    const int pr  = w * 8 + (lane >> 3);           // prow (0..63)
    const int q   = (lane & 7) ^ (pr & 7);
    const int a_s = (q >> 2) & 1, lk_s = q & 3;
    const unsigned short* sAa = A + (size_t)(rowBase + 2 * pr + a_s) * K_DIM + lk_s * 8;
    const unsigned short* sBa = B + (size_t)(colBase + 2 * pr + a_s) * K_DIM + lk_s * 8;

    // ---- read-side offsets (R9 verbatim) ----
    const int pcol = (((lr & 1) << 2) + lk) ^ (lr >> 1);
    const int offA = (wm * 64 + (lr >> 1)) * 128 + pcol * 16;            // A region +0
    const int offB = 16384 + (wn * 32 + (lr >> 1)) * 128 + pcol * 16;    // B region +16KB

#define AS1 __attribute__((address_space(1)))
#define AS3 __attribute__((address_space(3)))
#define STG(src, dst) \
    __builtin_amdgcn_global_load_lds((const AS1 void*)(src), \
        (AS3 void*)(lds + (dst) + w * 1024), 16, 0, 0)
// stage K-tile (T+3) into buf (T+3)&3 (4 loads/thread)
#define STAGE4(T) do { \
    const int _o = (((T) + 3) & 3) * 32768; \
    const unsigned short* _a = sAa + ((T) + 3) * 32; \
    const unsigned short* _b = sBa + ((T) + 3) * 32; \
    STG(_a, _o); STG(_a + IOFF, _o + 8192); \
    STG(_b, _o + 16384); STG(_b + IOFF, _o + 24576); } while (0)

#define BAR()   __builtin_amdgcn_s_barrier()
#define VM0()   asm volatile("s_waitcnt vmcnt(0)" ::: "memory")
#define VM4()   asm volatile("s_waitcnt vmcnt(4)" ::: "memory")
#define PRIO1() __builtin_amdgcn_s_setprio(1)
#define PRIO0() __builtin_amdgcn_s_setprio(0)

    f32x4 acc[8][4];
#pragma unroll
    for (int m = 0; m < 8; ++m)
#pragma unroll
        for (int n = 0; n < 4; ++n) acc[m][n] = (f32x4)0.f;

    // two register fragment sets (ping-pong across tiles)
    bf16x8 aR[8], bR[4], aS[8], bS[4];

#define RDT(AD, BD, bo) do { \
    _Pragma("unroll") for (int n = 0; n < 4; ++n) \
        BD[n] = *(const bf16x8*)(lds + (bo) + offB + n * 1024); \
    _Pragma("unroll") for (int m = 0; m < 8; ++m) \
        AD[m] = *(const bf16x8*)(lds + (bo) + offA + m * 1024); } while (0)

#define MF32(AF, BF) do { \
    _Pragma("unroll") for (int m = 0; m < 8; ++m) \
    _Pragma("unroll") for (int n = 0; n < 4; ++n) \
        acc[m][n] = __builtin_amdgcn_mfma_f32_16x16x32_bf16(AF[m], BF[n], acc[m][n], 0, 0, 0); } while (0)

    // body: stage T+3; read frags of T+1 into (AN,BN); MFMA on (AC,BC); VM4; BAR
#define TILE_S(T, AC, BC, AN, BN) do { \
    STAGE4(T); RDT(AN, BN, (((T) + 1) & 3) * 32768); \
    PRIO1(); MF32(AC, BC); PRIO0(); VM4(); BAR(); } while (0)

    // ---- prologue: stage tiles 0,1,2; VM4 drains bufs 0,1; read tile0 frags ----
    STAGE4(-3); STAGE4(-2); STAGE4(-1);
    VM4(); BAR();
    RDT(aR, bR, 0);

    // ---- main: tiles 0..59 (T8 % 4 == 0 keeps buffer offsets compile-time) ----
#pragma unroll 1
    for (int T8 = 0; T8 < 60; T8 += 4) {
        TILE_S(T8 + 0, aR, bR, aS, bS);
        TILE_S(T8 + 1, aS, bS, aR, bR);
        TILE_S(T8 + 2, aR, bR, aS, bS);
        TILE_S(T8 + 3, aS, bS, aR, bR);
    }
    // ---- T=60: last staged tile (stages buf 63) ----
    TILE_S(60, aR, bR, aS, bS);
    // ---- T=61: reads 62; VM0 drains T=60's stage (buf 63) ----
    RDT(aR, bR, 2 * 32768);
    PRIO1(); MF32(aS, bS); PRIO0(); VM0(); BAR();
    // ---- T=62: reads 63 ----
    RDT(aS, bS, 3 * 32768);
    PRIO1(); MF32(aR, bR); PRIO0(); BAR();
    // ---- T=63 ----
    PRIO1(); MF32(aS, bS); PRIO0();

    // ---- epilogue: + bias, store bf16. C/D: col = lane&15, row = lk*4 + reg ----
    float bb[4];
#pragma unroll
    for (int n = 0; n < 4; ++n) {
        int col = colBase + wn * 64 + n * 16 + lr;
        bb[n] = (col < NN) ? bias[col] : 0.f;
    }
#pragma unroll
    for (int m = 0; m < 8; ++m) {
        int rowb = rowBase + wm * 128 + m * 16 + lk * 4;
#pragma unroll
        for (int j = 0; j < 4; ++j) {
            unsigned short* xr = X + (size_t)(rowb + j) * NPAD + colBase + wn * 64 + lr;
#pragma unroll
            for (int n = 0; n < 4; ++n)
                xr[n * 16] = f2bf(acc[m][n][j] + bb[n]);
        }
    }
}

// ---------------- tree kernel: out[b,a] = S_abs[b] - min_{leaf≡a mod 10} pathPenalty ----------------
__global__ __launch_bounds__(256) void tree_kernel(const unsigned short* __restrict__ X,
                                                   float* __restrict__ out) {
    __shared__ float xs[4][2048];
    __shared__ float cm[4][64][ODIM];
    const int w    = threadIdx.x >> 6;
    const int lane = threadIdx.x & 63;
    const int row  = blockIdx.x * 4 + w;
    const unsigned short* xr = X + (size_t)row * NPAD;

#pragma unroll
    for (int i = 0; i < 4; ++i) {
        int base = i * 512 + lane * 8;
        uint4 v = *(const uint4*)(xr + base);
        const unsigned short* h = (const unsigned short*)&v;
#pragma unroll
        for (int j = 0; j < 8; ++j) xs[w][base + j] = bf2f(h[j]);
    }
    __syncthreads();

    float sabs = 0.f;
#pragma unroll
    for (int i = 0; i < 32; ++i) sabs += fabsf(xs[w][lane + i * 64]);
#pragma unroll
    for (int d = 1; d < 64; d <<= 1) sabs += __shfl_xor(sabs, d, 64);

    const int L = lane;
    float bp = 0.f;
#pragma unroll
    for (int l = 0; l <= 5; ++l) {
        float v = xs[w][(1 << l) - 1 + (L >> (6 - l))];
        bp += ((L >> (5 - l)) & 1) ? fmaxf(v, 0.f) : fmaxf(-v, 0.f);
    }
    float p2[2], p4[4], p8[8], p16[16], p32[32];
    {
        float v = xs[w][63 + L];
        p2[0] = bp + fmaxf(-v, 0.f);
        p2[1] = bp + fmaxf(v, 0.f);
    }
#pragma unroll
    for (int c = 0; c < 2; ++c) {
        float v = xs[w][127 + 2 * L + c];
        p4[2 * c]     = p2[c] + fmaxf(-v, 0.f);
        p4[2 * c + 1] = p2[c] + fmaxf(v, 0.f);
    }
#pragma unroll
    for (int c = 0; c < 4; ++c) {
        float v = xs[w][255 + 4 * L + c];
        p8[2 * c]     = p4[c] + fmaxf(-v, 0.f);
        p8[2 * c + 1] = p4[c] + fmaxf(v, 0.f);
    }
#pragma unroll
    for (int c = 0; c < 8; ++c) {
        float v = xs[w][511 + 8 * L + c];
        p16[2 * c]     = p8[c] + fmaxf(-v, 0.f);
        p16[2 * c + 1] = p8[c] + fmaxf(v, 0.f);
    }
#pragma unroll
    for (int c = 0; c < 16; ++c) {
        float v = xs[w][1023 + 16 * L + c];
        p32[2 * c]     = p16[c] + fmaxf(-v, 0.f);
        p32[2 * c + 1] = p16[c] + fmaxf(v, 0.f);
    }

    float m[ODIM];
#pragma unroll
    for (int r = 0; r < ODIM; ++r) m[r] = 1e30f;
#pragma unroll
    for (int tt = 0; tt < 32; ++tt) m[tt % ODIM] = fminf(m[tt % ODIM], p32[tt]);

    int base_mod = (L * 32) % ODIM;
#pragma unroll
    for (int r = 0; r < ODIM; ++r) {
        int a = base_mod + r; if (a >= ODIM) a -= ODIM;
        cm[w][L][a] = m[r];
    }
    __syncthreads();

    if (lane < ODIM) {
        float mn = 1e30f;
        for (int l2 = 0; l2 < 64; ++l2) mn = fminf(mn, cm[w][l2][lane]);
        out[(size_t)row * ODIM + lane] = sabs - mn;
    }
}

extern "C" void kernel_launch(void* const* d_in, const int* in_sizes, int n_in,
                              void* d_out, int out_size, void* d_ws, size_t ws_size,
                              hipStream_t stream) {
    const float* in_x = (const float*)d_in[0];
    const float* W1   = (const float*)d_in[1];
    const float* b1   = (const float*)d_in[2];

    unsigned short* Abf = (unsigned short*)d_ws;                      // 16384*2048 bf16
    unsigned short* Wbf = Abf + (size_t)BATCH * K_DIM;                // 2048*2048 bf16
    unsigned short* Xbf = Wbf + (size_t)NPAD * K_DIM;                 // 16384*2048 bf16
    float* out = (float*)d_out;

    cvt_all<<<18432, 256, 0, stream>>>(in_x, W1, Abf, Wbf);
    gemmK<<<512, 512, 0, stream>>>(Abf, Wbf, b1, Xbf);
    tree_kernel<<<BATCH / 4, 256, 0, stream>>>(Xbf, out);
}

// Round 11
// 204.455 us; speedup vs baseline: 1.0042x; 1.0042x over previous
//
#include <hip/hip_runtime.h>
#include <stdint.h>

// Problem constants
#define K_DIM   2048      // IN_DIM
#define NN      2047      // N_NODES
#define NPAD    2048      // padded node dim
#define BATCH   16384
#define ODIM    10
#define IOFF    (128 * 2048)   // +128 rows in elements

typedef __attribute__((ext_vector_type(8))) short  bf16x8;
typedef __attribute__((ext_vector_type(4))) float  f32x4;

static __device__ __forceinline__ unsigned short f2bf(float f) {
    union { float f; unsigned int u; } c; c.f = f;
    unsigned int u = c.u;
    return (unsigned short)((u + 0x7fffu + ((u >> 16) & 1u)) >> 16);
}
static __device__ __forceinline__ float bf2f(unsigned short h) {
    union { unsigned int u; float f; } c; c.u = ((unsigned int)h) << 16;
    return c.f;
}

// ---------------- fused fp32 -> bf16 conversion: in_x and padded W1 ----------------
__global__ __launch_bounds__(256) void cvt_all(const float* __restrict__ xs,
                                               const float* __restrict__ ws,
                                               unsigned short* __restrict__ dx,
                                               unsigned short* __restrict__ dw) {
    int b = blockIdx.x;
    union { unsigned short h[8]; uint4 v; } o;
    if (b < 16384) {
        int i = b * 256 + threadIdx.x;
        const float4* s = (const float4*)xs + (size_t)i * 2;
        float4 a = s[0], c = s[1];
        o.h[0] = f2bf(a.x); o.h[1] = f2bf(a.y); o.h[2] = f2bf(a.z); o.h[3] = f2bf(a.w);
        o.h[4] = f2bf(c.x); o.h[5] = f2bf(c.y); o.h[6] = f2bf(c.z); o.h[7] = f2bf(c.w);
        *((uint4*)dx + i) = o.v;
    } else {
        int i = (b - 16384) * 256 + threadIdx.x;
        size_t e = (size_t)i * 8;
        int row = (int)(e >> 11);
        if (row < NN) {
            const float4* s = (const float4*)(ws + e);
            float4 a = s[0], c = s[1];
            o.h[0] = f2bf(a.x); o.h[1] = f2bf(a.y); o.h[2] = f2bf(a.z); o.h[3] = f2bf(a.w);
            o.h[4] = f2bf(c.x); o.h[5] = f2bf(c.y); o.h[6] = f2bf(c.z); o.h[7] = f2bf(c.w);
        } else {
            o.v = make_uint4(0u, 0u, 0u, 0u);
        }
        *((uint4*)dw + i) = o.v;
    }
}

// ---------------- 256x256 bf16 GEMM, BK=32, 4 LDS bufs, register double-buffered frags ----------------
// Tile T: [stage(T+3) | ds_read frags of T+1 -> R_nxt | SB0 | MFMA on R_cur (no lgkm dep) | VM4 | BAR].
// amdgpu_waves_per_eu(2,2): 8 waves/wg = 2/SIMD forced by geometry -> 256-VGPR budget; stop the
// allocator's 128-reg heuristic that spilled R10 (+12MB scratch, VM4 semantics polluted).
__global__ __launch_bounds__(512) __attribute__((amdgpu_waves_per_eu(2, 2)))
void gemmK(const unsigned short* __restrict__ A,
           const unsigned short* __restrict__ B,
           const float* __restrict__ bias,
           unsigned short* __restrict__ X) {
    __shared__ char lds[131072];   // 4 bufs x (A 16KB + B 16KB)

    const int t0   = threadIdx.x;
    const int w    = t0 >> 6;
    const int lane = t0 & 63;
    const int wm = w >> 2, wn = w & 3;     // wave -> 128 rows x 64 cols
    const int lr = lane & 15, lk = lane >> 4;

    // XCD-aware swizzle: 512 wgs, 64 per XCD
    int bid = blockIdx.x;
    int swz = (bid & 7) * 64 + (bid >> 3);
    const int rowBase = (swz >> 3) * 256;  // 64 row-tiles
    const int colBase = (swz & 7) * 256;   // 8 col-tiles

    // ---- staging source (inverse-swizzled), R9 verbatim ----
    const int pr  = w * 8 + (lane >> 3);           // prow (0..63)
    const int q   = (lane & 7) ^ (pr & 7);
    const int a_s = (q >> 2) & 1, lk_s = q & 3;
    const unsigned short* sAa = A + (size_t)(rowBase + 2 * pr + a_s) * K_DIM + lk_s * 8;
    const unsigned short* sBa = B + (size_t)(colBase + 2 * pr + a_s) * K_DIM + lk_s * 8;

    // ---- read-side offsets (R9 verbatim) ----
    const int pcol = (((lr & 1) << 2) + lk) ^ (lr >> 1);
    const int offA = (wm * 64 + (lr >> 1)) * 128 + pcol * 16;            // A region +0
    const int offB = 16384 + (wn * 32 + (lr >> 1)) * 128 + pcol * 16;    // B region +16KB

#define AS1 __attribute__((address_space(1)))
#define AS3 __attribute__((address_space(3)))
#define STG(src, dst) \
    __builtin_amdgcn_global_load_lds((const AS1 void*)(src), \
        (AS3 void*)(lds + (dst) + w * 1024), 16, 0, 0)
// stage K-tile (T+3) into buf (T+3)&3 (4 loads/thread)
#define STAGE4(T) do { \
    const int _o = (((T) + 3) & 3) * 32768; \
    const unsigned short* _a = sAa + ((T) + 3) * 32; \
    const unsigned short* _b = sBa + ((T) + 3) * 32; \
    STG(_a, _o); STG(_a + IOFF, _o + 8192); \
    STG(_b, _o + 16384); STG(_b + IOFF, _o + 24576); } while (0)

#define BAR()   __builtin_amdgcn_s_barrier()
#define SB0()   __builtin_amdgcn_sched_barrier(0)
#define VM0()   asm volatile("s_waitcnt vmcnt(0)" ::: "memory")
#define VM4()   asm volatile("s_waitcnt vmcnt(4)" ::: "memory")
#define PRIO1() __builtin_amdgcn_s_setprio(1)
#define PRIO0() __builtin_amdgcn_s_setprio(0)

    f32x4 acc[8][4];
#pragma unroll
    for (int m = 0; m < 8; ++m)
#pragma unroll
        for (int n = 0; n < 4; ++n) acc[m][n] = (f32x4)0.f;

    // two register fragment sets (ping-pong across tiles)
    bf16x8 aR[8], bR[4], aS[8], bS[4];

#define RDT(AD, BD, bo) do { \
    _Pragma("unroll") for (int n = 0; n < 4; ++n) \
        BD[n] = *(const bf16x8*)(lds + (bo) + offB + n * 1024); \
    _Pragma("unroll") for (int m = 0; m < 8; ++m) \
        AD[m] = *(const bf16x8*)(lds + (bo) + offA + m * 1024); } while (0)

#define MF32(AF, BF) do { \
    _Pragma("unroll") for (int m = 0; m < 8; ++m) \
    _Pragma("unroll") for (int n = 0; n < 4; ++n) \
        acc[m][n] = __builtin_amdgcn_mfma_f32_16x16x32_bf16(AF[m], BF[n], acc[m][n], 0, 0, 0); } while (0)

    // body: stage T+3; read frags of T+1 into (AN,BN); pin reads above MFMA; MFMA on (AC,BC)
#define TILE_S(T, AC, BC, AN, BN) do { \
    STAGE4(T); RDT(AN, BN, (((T) + 1) & 3) * 32768); SB0(); \
    PRIO1(); MF32(AC, BC); PRIO0(); VM4(); BAR(); } while (0)

    // ---- prologue: stage tiles 0,1,2; VM4 drains bufs 0,1; read tile0 frags ----
    STAGE4(-3); STAGE4(-2); STAGE4(-1);
    VM4(); BAR();
    RDT(aR, bR, 0);

    // ---- main: tiles 0..59 (T8 % 4 == 0 keeps buffer offsets compile-time) ----
#pragma unroll 1
    for (int T8 = 0; T8 < 60; T8 += 4) {
        TILE_S(T8 + 0, aR, bR, aS, bS);
        TILE_S(T8 + 1, aS, bS, aR, bR);
        TILE_S(T8 + 2, aR, bR, aS, bS);
        TILE_S(T8 + 3, aS, bS, aR, bR);
    }
    // ---- T=60: last staged tile (stages K-tile 63 into buf 3) ----
    TILE_S(60, aR, bR, aS, bS);
    // ---- T=61: reads 62 (buf 2); VM0 drains stage(63) ----
    RDT(aR, bR, 2 * 32768); SB0();
    PRIO1(); MF32(aS, bS); PRIO0(); VM0(); BAR();
    // ---- T=62: reads 63 (buf 3) ----
    RDT(aS, bS, 3 * 32768); SB0();
    PRIO1(); MF32(aR, bR); PRIO0(); BAR();
    // ---- T=63 ----
    PRIO1(); MF32(aS, bS); PRIO0();

    // ---- epilogue: + bias, store bf16. C/D: col = lane&15, row = lk*4 + reg ----
    float bb[4];
#pragma unroll
    for (int n = 0; n < 4; ++n) {
        int col = colBase + wn * 64 + n * 16 + lr;
        bb[n] = (col < NN) ? bias[col] : 0.f;
    }
#pragma unroll
    for (int m = 0; m < 8; ++m) {
        int rowb = rowBase + wm * 128 + m * 16 + lk * 4;
#pragma unroll
        for (int j = 0; j < 4; ++j) {
            unsigned short* xr = X + (size_t)(rowb + j) * NPAD + colBase + wn * 64 + lr;
#pragma unroll
            for (int n = 0; n < 4; ++n)
                xr[n * 16] = f2bf(acc[m][n][j] + bb[n]);
        }
    }
}

// ---------------- tree kernel: out[b,a] = S_abs[b] - min_{leaf≡a mod 10} pathPenalty ----------------
__global__ __launch_bounds__(256) void tree_kernel(const unsigned short* __restrict__ X,
                                                   float* __restrict__ out) {
    __shared__ float xs[4][2048];
    __shared__ float cm[4][64][ODIM];
    const int w    = threadIdx.x >> 6;
    const int lane = threadIdx.x & 63;
    const int row  = blockIdx.x * 4 + w;
    const unsigned short* xr = X + (size_t)row * NPAD;

#pragma unroll
    for (int i = 0; i < 4; ++i) {
        int base = i * 512 + lane * 8;
        uint4 v = *(const uint4*)(xr + base);
        const unsigned short* h = (const unsigned short*)&v;
#pragma unroll
        for (int j = 0; j < 8; ++j) xs[w][base + j] = bf2f(h[j]);
    }
    __syncthreads();

    float sabs = 0.f;
#pragma unroll
    for (int i = 0; i < 32; ++i) sabs += fabsf(xs[w][lane + i * 64]);
#pragma unroll
    for (int d = 1; d < 64; d <<= 1) sabs += __shfl_xor(sabs, d, 64);

    const int L = lane;
    float bp = 0.f;
#pragma unroll
    for (int l = 0; l <= 5; ++l) {
        float v = xs[w][(1 << l) - 1 + (L >> (6 - l))];
        bp += ((L >> (5 - l)) & 1) ? fmaxf(v, 0.f) : fmaxf(-v, 0.f);
    }
    float p2[2], p4[4], p8[8], p16[16], p32[32];
    {
        float v = xs[w][63 + L];
        p2[0] = bp + fmaxf(-v, 0.f);
        p2[1] = bp + fmaxf(v, 0.f);
    }
#pragma unroll
    for (int c = 0; c < 2; ++c) {
        float v = xs[w][127 + 2 * L + c];
        p4[2 * c]     = p2[c] + fmaxf(-v, 0.f);
        p4[2 * c + 1] = p2[c] + fmaxf(v, 0.f);
    }
#pragma unroll
    for (int c = 0; c < 4; ++c) {
        float v = xs[w][255 + 4 * L + c];
        p8[2 * c]     = p4[c] + fmaxf(-v, 0.f);
        p8[2 * c + 1] = p4[c] + fmaxf(v, 0.f);
    }
#pragma unroll
    for (int c = 0; c < 8; ++c) {
        float v = xs[w][511 + 8 * L + c];
        p16[2 * c]     = p8[c] + fmaxf(-v, 0.f);
        p16[2 * c + 1] = p8[c] + fmaxf(v, 0.f);
    }
#pragma unroll
    for (int c = 0; c < 16; ++c) {
        float v = xs[w][1023 + 16 * L + c];
        p32[2 * c]     = p16[c] + fmaxf(-v, 0.f);
        p32[2 * c + 1] = p16[c] + fmaxf(v, 0.f);
    }

    float m[ODIM];
#pragma unroll
    for (int r = 0; r < ODIM; ++r) m[r] = 1e30f;
#pragma unroll
    for (int tt = 0; tt < 32; ++tt) m[tt % ODIM] = fminf(m[tt % ODIM], p32[tt]);

    int base_mod = (L * 32) % ODIM;
#pragma unroll
    for (int r = 0; r < ODIM; ++r) {
        int a = base_mod + r; if (a >= ODIM) a -= ODIM;
        cm[w][L][a] = m[r];
    }
    __syncthreads();

    if (lane < ODIM) {
        float mn = 1e30f;
        for (int l2 = 0; l2 < 64; ++l2) mn = fminf(mn, cm[w][l2][lane]);
        out[(size_t)row * ODIM + lane] = sabs - mn;
    }
}

extern "C" void kernel_launch(void* const* d_in, const int* in_sizes, int n_in,
                              void* d_out, int out_size, void* d_ws, size_t ws_size,
                              hipStream_t stream) {
    const float* in_x = (const float*)d_in[0];
    const float* W1   = (const float*)d_in[1];
    const float* b1   = (const float*)d_in[2];

    unsigned short* Abf = (unsigned short*)d_ws;                      // 16384*2048 bf16
    unsigned short* Wbf = Abf + (size_t)BATCH * K_DIM;                // 2048*2048 bf16
    unsigned short* Xbf = Wbf + (size_t)NPAD * K_DIM;                 // 16384*2048 bf16
    float* out = (float*)d_out;

    cvt_all<<<18432, 256, 0, stream>>>(in_x, W1, Abf, Wbf);
    gemmK<<<512, 512, 0, stream>>>(Abf, Wbf, b1, Xbf);
    tree_kernel<<<BATCH / 4, 256, 0, stream>>>(Xbf, out);
}

// Round 12
// 191.117 us; speedup vs baseline: 1.0743x; 1.0698x over previous
//
#include <hip/hip_runtime.h>
#include <stdint.h>

// Problem constants
#define K_DIM   2048      // IN_DIM
#define NN      2047      // N_NODES
#define NPAD    2048      // padded node dim
#define BATCH   16384
#define ODIM    10
#define IOFF    (128 * 2048)   // +128 rows in elements

typedef __attribute__((ext_vector_type(8))) short  bf16x8;
typedef __attribute__((ext_vector_type(4))) float  f32x4;

static __device__ __forceinline__ unsigned short f2bf(float f) {
    union { float f; unsigned int u; } c; c.f = f;
    unsigned int u = c.u;
    return (unsigned short)((u + 0x7fffu + ((u >> 16) & 1u)) >> 16);
}
static __device__ __forceinline__ float bf2f(unsigned short h) {
    union { unsigned int u; float f; } c; c.u = ((unsigned int)h) << 16;
    return c.f;
}

// ---------------- fused fp32 -> bf16 conversion: in_x and padded W1 ----------------
__global__ __launch_bounds__(256) void cvt_all(const float* __restrict__ xs,
                                               const float* __restrict__ ws,
                                               unsigned short* __restrict__ dx,
                                               unsigned short* __restrict__ dw) {
    int b = blockIdx.x;
    union { unsigned short h[8]; uint4 v; } o;
    if (b < 16384) {
        int i = b * 256 + threadIdx.x;
        const float4* s = (const float4*)xs + (size_t)i * 2;
        float4 a = s[0], c = s[1];
        o.h[0] = f2bf(a.x); o.h[1] = f2bf(a.y); o.h[2] = f2bf(a.z); o.h[3] = f2bf(a.w);
        o.h[4] = f2bf(c.x); o.h[5] = f2bf(c.y); o.h[6] = f2bf(c.z); o.h[7] = f2bf(c.w);
        *((uint4*)dx + i) = o.v;
    } else {
        int i = (b - 16384) * 256 + threadIdx.x;
        size_t e = (size_t)i * 8;
        int row = (int)(e >> 11);
        if (row < NN) {
            const float4* s = (const float4*)(ws + e);
            float4 a = s[0], c = s[1];
            o.h[0] = f2bf(a.x); o.h[1] = f2bf(a.y); o.h[2] = f2bf(a.z); o.h[3] = f2bf(a.w);
            o.h[4] = f2bf(c.x); o.h[5] = f2bf(c.y); o.h[6] = f2bf(c.z); o.h[7] = f2bf(c.w);
        } else {
            o.v = make_uint4(0u, 0u, 0u, 0u);
        }
        *((uint4*)dw + i) = o.v;
    }
}

// ---------------- 256x256 bf16 GEMM, BK=32, 4 LDS bufs, group-pipelined reads ----------------
// Tile T: [stage(T+3) | rd a0,a1 | {rd a(i+2); MFMA group i (aF[i] x bC)} | B(T+1)->bN under
// groups 4-5 | VM4 | BAR]. Only B is cross-tile reg-dbuf'd (+16 VGPR); A-frag liveness ~3
// groups. Counted lgkm per-use (compiler) pipelines reads under MFMA stream.
__global__ __launch_bounds__(512, 1) void gemmK(const unsigned short* __restrict__ A,
                                                const unsigned short* __restrict__ B,
                                                const float* __restrict__ bias,
                                                unsigned short* __restrict__ X) {
    __shared__ char lds[131072];   // 4 bufs x (A 16KB + B 16KB)

    const int t0   = threadIdx.x;
    const int w    = t0 >> 6;
    const int lane = t0 & 63;
    const int wm = w >> 2, wn = w & 3;     // wave -> 128 rows x 64 cols
    const int lr = lane & 15, lk = lane >> 4;

    // XCD-aware swizzle: 512 wgs, 64 per XCD
    int bid = blockIdx.x;
    int swz = (bid & 7) * 64 + (bid >> 3);
    const int rowBase = (swz >> 3) * 256;  // 64 row-tiles
    const int colBase = (swz & 7) * 256;   // 8 col-tiles

    // ---- staging source (inverse-swizzled), R9 verbatim ----
    const int pr  = w * 8 + (lane >> 3);           // prow (0..63)
    const int q   = (lane & 7) ^ (pr & 7);
    const int a_s = (q >> 2) & 1, lk_s = q & 3;
    const unsigned short* sAa = A + (size_t)(rowBase + 2 * pr + a_s) * K_DIM + lk_s * 8;
    const unsigned short* sBa = B + (size_t)(colBase + 2 * pr + a_s) * K_DIM + lk_s * 8;

    // ---- read-side offsets (R9 verbatim) ----
    const int pcol = (((lr & 1) << 2) + lk) ^ (lr >> 1);
    const int offA = (wm * 64 + (lr >> 1)) * 128 + pcol * 16;            // A region +0
    const int offB = 16384 + (wn * 32 + (lr >> 1)) * 128 + pcol * 16;    // B region +16KB

#define AS1 __attribute__((address_space(1)))
#define AS3 __attribute__((address_space(3)))
#define STG(src, dst) \
    __builtin_amdgcn_global_load_lds((const AS1 void*)(src), \
        (AS3 void*)(lds + (dst) + w * 1024), 16, 0, 0)
// stage K-tile (T+3) into buf (T+3)&3 (4 loads/thread)
#define STAGE4(T) do { \
    const int _o = (((T) + 3) & 3) * 32768; \
    const unsigned short* _a = sAa + ((T) + 3) * 32; \
    const unsigned short* _b = sBa + ((T) + 3) * 32; \
    STG(_a, _o); STG(_a + IOFF, _o + 8192); \
    STG(_b, _o + 16384); STG(_b + IOFF, _o + 24576); } while (0)

#define BAR()   __builtin_amdgcn_s_barrier()
#define VM0()   asm volatile("s_waitcnt vmcnt(0)" ::: "memory")
#define VM4()   asm volatile("s_waitcnt vmcnt(4)" ::: "memory")
#define PRIO1() __builtin_amdgcn_s_setprio(1)
#define PRIO0() __builtin_amdgcn_s_setprio(0)

    f32x4 acc[8][4];
#pragma unroll
    for (int m = 0; m < 8; ++m)
#pragma unroll
        for (int n = 0; n < 4; ++n) acc[m][n] = (f32x4)0.f;

    bf16x8 aF[8];          // A fragments, group-pipelined (liveness ~3)
    bf16x8 bX[4], bY[4];   // B ping-pong (cross-tile dbuf)

#define RDA(i, bo) aF[i] = *(const bf16x8*)(lds + (bo) + offA + (i) * 1024)
#define RDB(BD, j, bo) BD[j] = *(const bf16x8*)(lds + (bo) + offB + (j) * 1024)

#define MFG(i, BF) do { \
    _Pragma("unroll") for (int n = 0; n < 4; ++n) \
        acc[i][n] = __builtin_amdgcn_mfma_f32_16x16x32_bf16(aF[i], BF[n], acc[i][n], 0, 0, 0); } while (0)

    // body: stage T+3; group-pipelined A reads + MFMA on (aF, BC); prefetch B(T+1)->BN
#define TILE_B(T, BC, BN) do { \
    const int _bo = ((T) & 3) * 32768, _bn = (((T) + 1) & 3) * 32768; \
    STAGE4(T); \
    RDA(0, _bo); RDA(1, _bo); \
    PRIO1(); \
    RDA(2, _bo); MFG(0, BC); \
    RDA(3, _bo); MFG(1, BC); \
    RDA(4, _bo); MFG(2, BC); \
    RDA(5, _bo); MFG(3, BC); \
    RDA(6, _bo); RDB(BN, 0, _bn); RDB(BN, 1, _bn); MFG(4, BC); \
    RDA(7, _bo); RDB(BN, 2, _bn); RDB(BN, 3, _bn); MFG(5, BC); \
    MFG(6, BC); MFG(7, BC); \
    PRIO0(); VM4(); BAR(); } while (0)

    // ---- prologue: stage tiles 0,1,2; VM4 retires bufs 0,1; pre-read B(0) ----
    STAGE4(-3); STAGE4(-2); STAGE4(-1);
    VM4(); BAR();
    RDB(bX, 0, 0); RDB(bX, 1, 0); RDB(bX, 2, 0); RDB(bX, 3, 0);

    // ---- main: tiles 0..59 staged (T8 % 4 == 0 keeps buf offsets compile-time) ----
#pragma unroll 1
    for (int T8 = 0; T8 < 60; T8 += 4) {
        TILE_B(T8 + 0, bX, bY);
        TILE_B(T8 + 1, bY, bX);
        TILE_B(T8 + 2, bX, bY);
        TILE_B(T8 + 3, bY, bX);
    }
    // ---- T=60 (even: C=bX): last staged tile (stages K-tile 63 into buf 3) ----
    TILE_B(60, bX, bY);
    // ---- T=61 (C=bY): no stage; prefetch B(62) from buf 2; VM0 drains stage(63) ----
    {
        const int _bo = 1 * 32768, _bn = 2 * 32768;
        RDA(0, _bo); RDA(1, _bo);
        PRIO1();
        RDA(2, _bo); MFG(0, bY);
        RDA(3, _bo); MFG(1, bY);
        RDA(4, _bo); MFG(2, bY);
        RDA(5, _bo); MFG(3, bY);
        RDA(6, _bo); RDB(bX, 0, _bn); RDB(bX, 1, _bn); MFG(4, bY);
        RDA(7, _bo); RDB(bX, 2, _bn); RDB(bX, 3, _bn); MFG(5, bY);
        MFG(6, bY); MFG(7, bY);
        PRIO0(); VM0(); BAR();
    }
    // ---- T=62 (C=bX): prefetch B(63) from buf 3 ----
    {
        const int _bo = 2 * 32768, _bn = 3 * 32768;
        RDA(0, _bo); RDA(1, _bo);
        PRIO1();
        RDA(2, _bo); MFG(0, bX);
        RDA(3, _bo); MFG(1, bX);
        RDA(4, _bo); MFG(2, bX);
        RDA(5, _bo); MFG(3, bX);
        RDA(6, _bo); RDB(bY, 0, _bn); RDB(bY, 1, _bn); MFG(4, bX);
        RDA(7, _bo); RDB(bY, 2, _bn); RDB(bY, 3, _bn); MFG(5, bX);
        MFG(6, bX); MFG(7, bX);
        PRIO0(); BAR();
    }
    // ---- T=63 (C=bY): no stage, no prefetch ----
    {
        const int _bo = 3 * 32768;
        RDA(0, _bo); RDA(1, _bo);
        PRIO1();
        RDA(2, _bo); MFG(0, bY);
        RDA(3, _bo); MFG(1, bY);
        RDA(4, _bo); MFG(2, bY);
        RDA(5, _bo); MFG(3, bY);
        RDA(6, _bo); MFG(4, bY);
        RDA(7, _bo); MFG(5, bY);
        MFG(6, bY); MFG(7, bY);
        PRIO0();
    }

    // ---- epilogue: + bias, store bf16. C/D: col = lane&15, row = lk*4 + reg ----
    float bb[4];
#pragma unroll
    for (int n = 0; n < 4; ++n) {
        int col = colBase + wn * 64 + n * 16 + lr;
        bb[n] = (col < NN) ? bias[col] : 0.f;
    }
#pragma unroll
    for (int m = 0; m < 8; ++m) {
        int rowb = rowBase + wm * 128 + m * 16 + lk * 4;
#pragma unroll
        for (int j = 0; j < 4; ++j) {
            unsigned short* xr = X + (size_t)(rowb + j) * NPAD + colBase + wn * 64 + lr;
#pragma unroll
            for (int n = 0; n < 4; ++n)
                xr[n * 16] = f2bf(acc[m][n][j] + bb[n]);
        }
    }
}

// ---------------- tree kernel: out[b,a] = S_abs[b] - min_{leaf≡a mod 10} pathPenalty ----------------
__global__ __launch_bounds__(256) void tree_kernel(const unsigned short* __restrict__ X,
                                                   float* __restrict__ out) {
    __shared__ float xs[4][2048];
    __shared__ float cm[4][64][ODIM];
    const int w    = threadIdx.x >> 6;
    const int lane = threadIdx.x & 63;
    const int row  = blockIdx.x * 4 + w;
    const unsigned short* xr = X + (size_t)row * NPAD;

#pragma unroll
    for (int i = 0; i < 4; ++i) {
        int base = i * 512 + lane * 8;
        uint4 v = *(const uint4*)(xr + base);
        const unsigned short* h = (const unsigned short*)&v;
#pragma unroll
        for (int j = 0; j < 8; ++j) xs[w][base + j] = bf2f(h[j]);
    }
    __syncthreads();

    float sabs = 0.f;
#pragma unroll
    for (int i = 0; i < 32; ++i) sabs += fabsf(xs[w][lane + i * 64]);
#pragma unroll
    for (int d = 1; d < 64; d <<= 1) sabs += __shfl_xor(sabs, d, 64);

    const int L = lane;
    float bp = 0.f;
#pragma unroll
    for (int l = 0; l <= 5; ++l) {
        float v = xs[w][(1 << l) - 1 + (L >> (6 - l))];
        bp += ((L >> (5 - l)) & 1) ? fmaxf(v, 0.f) : fmaxf(-v, 0.f);
    }
    float p2[2], p4[4], p8[8], p16[16], p32[32];
    {
        float v = xs[w][63 + L];
        p2[0] = bp + fmaxf(-v, 0.f);
        p2[1] = bp + fmaxf(v, 0.f);
    }
#pragma unroll
    for (int c = 0; c < 2; ++c) {
        float v = xs[w][127 + 2 * L + c];
        p4[2 * c]     = p2[c] + fmaxf(-v, 0.f);
        p4[2 * c + 1] = p2[c] + fmaxf(v, 0.f);
    }
#pragma unroll
    for (int c = 0; c < 4; ++c) {
        float v = xs[w][255 + 4 * L + c];
        p8[2 * c]     = p4[c] + fmaxf(-v, 0.f);
        p8[2 * c + 1] = p4[c] + fmaxf(v, 0.f);
    }
#pragma unroll
    for (int c = 0; c < 8; ++c) {
        float v = xs[w][511 + 8 * L + c];
        p16[2 * c]     = p8[c] + fmaxf(-v, 0.f);
        p16[2 * c + 1] = p8[c] + fmaxf(v, 0.f);
    }
#pragma unroll
    for (int c = 0; c < 16; ++c) {
        float v = xs[w][1023 + 16 * L + c];
        p32[2 * c]     = p16[c] + fmaxf(-v, 0.f);
        p32[2 * c + 1] = p16[c] + fmaxf(v, 0.f);
    }

    float m[ODIM];
#pragma unroll
    for (int r = 0; r < ODIM; ++r) m[r] = 1e30f;
#pragma unroll
    for (int tt = 0; tt < 32; ++tt) m[tt % ODIM] = fminf(m[tt % ODIM], p32[tt]);

    int base_mod = (L * 32) % ODIM;
#pragma unroll
    for (int r = 0; r < ODIM; ++r) {
        int a = base_mod + r; if (a >= ODIM) a -= ODIM;
        cm[w][L][a] = m[r];
    }
    __syncthreads();

    if (lane < ODIM) {
        float mn = 1e30f;
        for (int l2 = 0; l2 < 64; ++l2) mn = fminf(mn, cm[w][l2][lane]);
        out[(size_t)row * ODIM + lane] = sabs - mn;
    }
}

extern "C" void kernel_launch(void* const* d_in, const int* in_sizes, int n_in,
                              void* d_out, int out_size, void* d_ws, size_t ws_size,
                              hipStream_t stream) {
    const float* in_x = (const float*)d_in[0];
    const float* W1   = (const float*)d_in[1];
    const float* b1   = (const float*)d_in[2];

    unsigned short* Abf = (unsigned short*)d_ws;                      // 16384*2048 bf16
    unsigned short* Wbf = Abf + (size_t)BATCH * K_DIM;                // 2048*2048 bf16
    unsigned short* Xbf = Wbf + (size_t)NPAD * K_DIM;                 // 16384*2048 bf16
    float* out = (float*)d_out;

    cvt_all<<<18432, 256, 0, stream>>>(in_x, W1, Abf, Wbf);
    gemmK<<<512, 512, 0, stream>>>(Abf, Wbf, b1, Xbf);
    tree_kernel<<<BATCH / 4, 256, 0, stream>>>(Xbf, out);
}